// Round 5
// baseline (210.511 us; speedup 1.0000x reference)
//
#include <hip/hip_runtime.h>
#include <hip/hip_bf16.h>

#define S_ 1024
#define D_ 128
#define V_ 100000
#define N_ 4096
#define VPAD_ 100352    // 1568 * 64  (pad rows zero -> exp2(0)=1 each)
#define NT64_ 1568      // 64-row K tiles; 1568/16 = 98 tiles per split (even)
#define NSPLIT_ 16      // grid (32,16) = 512 blocks = 2/CU
#define PADROWS_ 352.0f

typedef __attribute__((ext_vector_type(4))) float f32x4;
typedef __attribute__((ext_vector_type(8))) short bf16x8;

#define LOG2E_ 1.4426950408889634f
#define LN2_   0.6931471805599453f

__device__ __forceinline__ float exp2_fast(float x) {
#if __has_builtin(__builtin_amdgcn_exp2f)
    return __builtin_amdgcn_exp2f(x);
#else
    return exp2f(x);
#endif
}

// ---- kernel 1: normalize K rows -> bf16, zero-fill pad rows [V_, VPAD_) ----
__global__ void knorm_kernel(const float* __restrict__ K, __hip_bfloat16* __restrict__ Kn) {
    int w = (blockIdx.x * blockDim.x + threadIdx.x) >> 6;
    int lane = threadIdx.x & 63;
    if (w >= VPAD_) return;
    unsigned int* dst = (unsigned int*)(Kn + (size_t)w * D_);
    if (w >= V_) { dst[lane] = 0u; return; }
    float2 v = ((const float2*)(K + (size_t)w * D_))[lane];
    float ss = v.x * v.x + v.y * v.y;
    #pragma unroll
    for (int off = 32; off; off >>= 1) ss += __shfl_xor(ss, off);
    float rn = rsqrtf(ss);
    __hip_bfloat162 o;
    o.x = __float2bfloat16(v.x * rn);
    o.y = __float2bfloat16(v.y * rn);
    ((__hip_bfloat162*)dst)[lane] = o;
}

// ---- kernel 2: gather + normalize Q -> bf16 (pre-scaled by log2 e); zero Ssum ----
__global__ void qnorm_kernel(const float* __restrict__ Q, const int* __restrict__ loc,
                             __hip_bfloat16* __restrict__ Qn, float* __restrict__ Ssum) {
    int w = (blockIdx.x * blockDim.x + threadIdx.x) >> 6;
    int lane = threadIdx.x & 63;
    if (w >= N_) return;
    if (lane == 0) Ssum[w] = 0.f;          // re-zeroed every call (atomic target)
    int b = loc[2 * w], s = loc[2 * w + 1];
    float2 v = ((const float2*)(Q + ((size_t)b * S_ + (size_t)s) * D_))[lane];
    float ss = v.x * v.x + v.y * v.y;
    #pragma unroll
    for (int off = 32; off; off >>= 1) ss += __shfl_xor(ss, off);
    float rn = rsqrtf(ss) * LOG2E_;        // exp2 domain
    __hip_bfloat162 o;
    o.x = __float2bfloat16(v.x * rn);
    o.y = __float2bfloat16(v.y * rn);
    ((__hip_bfloat162*)(Qn + (size_t)w * D_))[lane] = o;
}

// ---- kernel 3: main  sum_v exp2(q . k_v)  -- NO LDS, NO BARRIERS ----
// K is L2/L3-resident (FETCH was 16.6MB): each wave loads its 8KB col-half
// per 64-row tile straight to registers (8x global_load_dwordx4, one base +
// imm offsets), double-buffered one tile ahead. Waves fully independent.
// Block 128q x 64v (4 waves); wave 64q x 32v (m=4, nn=2).
__global__ __launch_bounds__(256, 2) void ce_main(
    const __hip_bfloat16* __restrict__ Qn,
    const __hip_bfloat16* __restrict__ Kn,
    float* __restrict__ Ssum)
{
    const int tid  = threadIdx.x;
    const int lane = tid & 63;
    const int wv   = tid >> 6;
    const int wr   = wv >> 1;      // q-half
    const int wc   = wv & 1;       // v col-half

    // XCD-aware remap: each XCD owns 2 whole splits (all 32 nb of each)
    const int fid  = blockIdx.y * 32 + blockIdx.x;
    const int xcd  = fid & 7;
    const int idx  = fid >> 3;               // 0..63
    const int split = xcd * 2 + (idx >> 5);
    const int nb    = idx & 31;

    // ---- Q fragments -> registers (loop-invariant) ----
    bf16x8 afr[4][4];
    {
        const char* qsrc = (const char*)Qn + (size_t)nb * 32768
                         + (wr * 64 + (lane & 15)) * 256 + ((lane >> 4) << 4);
        #pragma unroll
        for (int m = 0; m < 4; ++m)
            #pragma unroll
            for (int kk = 0; kk < 4; ++kk)
                afr[m][kk] = *(const bf16x8*)(qsrc + m * 4096 + kk * 64);
    }

    // per-lane byte offset of this lane's fragment slot within a K tile
    const int klane = (wc * 32 + (lane & 15)) * 256 + ((lane >> 4) << 4);
    const char* kb = (const char*)Kn;

    float psumA[4][4], psumB[4][4];
    #pragma unroll
    for (int m = 0; m < 4; ++m)
        #pragma unroll
        for (int q = 0; q < 4; ++q) { psumA[m][q] = 0.f; psumB[m][q] = 0.f; }

    const f32x4 fz = {0.f, 0.f, 0.f, 0.f};

    // R[0..3] = nn=0 kk=0..3 (imm 0,64,128,192); R[4..7] = nn=1 (imm +4096)
#define LOADSET(R, TOFF) do {                                          \
        const char* p = kb + (klane + (TOFF));                         \
        R[0] = *(const bf16x8*)(p);        R[1] = *(const bf16x8*)(p + 64);   \
        R[2] = *(const bf16x8*)(p + 128);  R[3] = *(const bf16x8*)(p + 192);  \
        R[4] = *(const bf16x8*)(p + 4096); R[5] = *(const bf16x8*)(p + 4160); \
        R[6] = *(const bf16x8*)(p + 4224); R[7] = *(const bf16x8*)(p + 4288); \
    } while (0)

#define COMPUTE(R) do {                                                \
        f32x4 a0[4], a1[4];                                            \
        __builtin_amdgcn_s_setprio(1);                                 \
        _Pragma("unroll")                                              \
        for (int m = 0; m < 4; ++m) {                                  \
            a0[m] = __builtin_amdgcn_mfma_f32_16x16x32_bf16(afr[m][0], R[0], fz, 0, 0, 0); \
            a1[m] = __builtin_amdgcn_mfma_f32_16x16x32_bf16(afr[m][0], R[4], fz, 0, 0, 0); \
        }                                                              \
        _Pragma("unroll")                                              \
        for (int kk = 1; kk < 4; ++kk) {                               \
            _Pragma("unroll")                                          \
            for (int m = 0; m < 4; ++m) {                              \
                a0[m] = __builtin_amdgcn_mfma_f32_16x16x32_bf16(afr[m][kk], R[kk],     a0[m], 0, 0, 0); \
                a1[m] = __builtin_amdgcn_mfma_f32_16x16x32_bf16(afr[m][kk], R[4 + kk], a1[m], 0, 0, 0); \
            }                                                          \
        }                                                              \
        __builtin_amdgcn_s_setprio(0);                                 \
        _Pragma("unroll")                                              \
        for (int m = 0; m < 4; ++m) {                                  \
            _Pragma("unroll")                                          \
            for (int q = 0; q < 4; ++q) {                              \
                psumA[m][q] += exp2_fast(a0[m][q]);                    \
                psumB[m][q] += exp2_fast(a1[m][q]);                    \
            }                                                          \
        }                                                              \
    } while (0)

    bf16x8 RA[8], RB[8];
    const int step = 16384 * NSPLIT_;       // 262144 B per split-stride tile
    int t = split * 16384;
    LOADSET(RA, t);
    #pragma unroll 1
    for (int i = 0; i < 48; ++i) {          // 2 tiles per iteration
        LOADSET(RB, t + step);
        COMPUTE(RA);
        LOADSET(RA, t + 2 * step);
        COMPUTE(RB);
        t += 2 * step;
    }
    LOADSET(RB, t + step);                  // tile 97
    COMPUTE(RA);                            // tile 96
    COMPUTE(RB);                            // tile 97  -> total 98 tiles

#undef LOADSET
#undef COMPUTE

    // merge psum banks, reduce over 16 lanes (same rows), atomics
    #pragma unroll
    for (int m = 0; m < 4; ++m) {
        #pragma unroll
        for (int q = 0; q < 4; ++q) {
            float v = psumA[m][q] + psumB[m][q];
            v += __shfl_xor(v, 1);
            v += __shfl_xor(v, 2);
            v += __shfl_xor(v, 4);
            v += __shfl_xor(v, 8);
            if ((lane & 15) == 0) {
                int row = nb * 128 + wr * 64 + m * 16 + ((lane >> 4) << 2) + q;
                atomicAdd(&Ssum[row], v);
            }
        }
    }
}

// ---- kernel 4: per-row term = log(S - PADROWS) - true_logit ----
__global__ void term_kernel(const __hip_bfloat16* __restrict__ Qn,
                            const __hip_bfloat16* __restrict__ Kn,
                            const int* __restrict__ labels,
                            const float* __restrict__ Ssum,
                            float* __restrict__ T) {
    int w = (blockIdx.x * blockDim.x + threadIdx.x) >> 6;
    int lane = threadIdx.x & 63;
    if (w >= N_) return;
    int lab = labels[w];
    __hip_bfloat162 q2 = ((const __hip_bfloat162*)(Qn + (size_t)w * D_))[lane];
    __hip_bfloat162 k2 = ((const __hip_bfloat162*)(Kn + (size_t)lab * D_))[lane];
    float d = __bfloat162float(q2.x) * __bfloat162float(k2.x)
            + __bfloat162float(q2.y) * __bfloat162float(k2.y);
    #pragma unroll
    for (int off = 32; off; off >>= 1) d += __shfl_xor(d, off);
    if (lane == 0) T[w] = logf(Ssum[w] - PADROWS_) - d * LN2_;
}

// ---- kernel 5: mean over N ----
__global__ void reduce_kernel(const float* __restrict__ T, float* __restrict__ out) {
    __shared__ float sm[4];
    float s = 0.f;
    for (int i = threadIdx.x; i < N_; i += 256) s += T[i];
    #pragma unroll
    for (int off = 32; off; off >>= 1) s += __shfl_xor(s, off);
    if ((threadIdx.x & 63) == 0) sm[threadIdx.x >> 6] = s;
    __syncthreads();
    if (threadIdx.x == 0) out[0] = (sm[0] + sm[1] + sm[2] + sm[3]) * (1.0f / (float)N_);
}

extern "C" void kernel_launch(void* const* d_in, const int* in_sizes, int n_in,
                              void* d_out, int out_size, void* d_ws, size_t ws_size,
                              hipStream_t stream) {
    (void)in_sizes; (void)n_in; (void)out_size; (void)ws_size;
    const float* Q   = (const float*)d_in[0];
    const float* K   = (const float*)d_in[1];
    const int* loc   = (const int*)d_in[2];
    const int* labels= (const int*)d_in[3];
    float* out = (float*)d_out;

    char* ws = (char*)d_ws;
    __hip_bfloat16* Kn = (__hip_bfloat16*)ws;                       // VPAD_*128*2 = 25,690,112 B
    __hip_bfloat16* Qn = (__hip_bfloat16*)(ws + 25690112);          // N_*128*2   =  1,048,576 B
    float* Ssum        = (float*)(ws + 25690112 + 1048576);         // N_*4
    float* T           = Ssum + N_;                                  // N_*4

    knorm_kernel<<<VPAD_ / 4, 256, 0, stream>>>(K, Kn);
    qnorm_kernel<<<N_ / 4, 256, 0, stream>>>(Q, loc, Qn, Ssum);
    ce_main<<<dim3(32, NSPLIT_), 256, 0, stream>>>(Qn, Kn, Ssum);
    term_kernel<<<N_ / 4, 256, 0, stream>>>(Qn, Kn, labels, Ssum, T);
    reduce_kernel<<<1, 256, 0, stream>>>(T, out);
}

// Round 6
// 120.135 us; speedup vs baseline: 1.7523x; 1.7523x over previous
//
#include <hip/hip_runtime.h>
#include <hip/hip_bf16.h>

#define S_ 1024
#define D_ 128
#define V_ 100000
#define N_ 4096
#define VPAD_ 100352    // 1568 * 64  (pad rows zero -> exp2(0)=1 each)
#define NT64_ 1568      // 64-row K tiles; 1568/16 = 98 tiles per split
#define NSPLIT_ 16      // grid (32,16) = 512 blocks = 2/CU
#define PADROWS_ 352.0f

typedef __attribute__((ext_vector_type(4))) float f32x4;
typedef __attribute__((ext_vector_type(8))) short bf16x8;

#define LOG2E_ 1.4426950408889634f
#define LN2_   0.6931471805599453f

__device__ __forceinline__ void gload16(const void* g, void* l) {
    __builtin_amdgcn_global_load_lds(
        (const __attribute__((address_space(1))) void*)g,
        (__attribute__((address_space(3))) void*)l, 16, 0, 0);
}

__device__ __forceinline__ float exp2_fast(float x) {
#if __has_builtin(__builtin_amdgcn_exp2f)
    return __builtin_amdgcn_exp2f(x);
#else
    return exp2f(x);
#endif
}

// ---- kernel 1: normalize K rows -> bf16, zero-fill pad rows [V_, VPAD_) ----
__global__ void knorm_kernel(const float* __restrict__ K, __hip_bfloat16* __restrict__ Kn) {
    int w = (blockIdx.x * blockDim.x + threadIdx.x) >> 6;
    int lane = threadIdx.x & 63;
    if (w >= VPAD_) return;
    unsigned int* dst = (unsigned int*)(Kn + (size_t)w * D_);
    if (w >= V_) { dst[lane] = 0u; return; }
    float2 v = ((const float2*)(K + (size_t)w * D_))[lane];
    float ss = v.x * v.x + v.y * v.y;
    #pragma unroll
    for (int off = 32; off; off >>= 1) ss += __shfl_xor(ss, off);
    float rn = rsqrtf(ss);
    __hip_bfloat162 o;
    o.x = __float2bfloat16(v.x * rn);
    o.y = __float2bfloat16(v.y * rn);
    ((__hip_bfloat162*)dst)[lane] = o;
}

// ---- kernel 2: gather + normalize Q -> bf16 (pre-scaled by log2 e); zero Ssum ----
__global__ void qnorm_kernel(const float* __restrict__ Q, const int* __restrict__ loc,
                             __hip_bfloat16* __restrict__ Qn, float* __restrict__ Ssum) {
    int w = (blockIdx.x * blockDim.x + threadIdx.x) >> 6;
    int lane = threadIdx.x & 63;
    if (w >= N_) return;
    if (lane == 0) Ssum[w] = 0.f;
    int b = loc[2 * w], s = loc[2 * w + 1];
    float2 v = ((const float2*)(Q + ((size_t)b * S_ + (size_t)s) * D_))[lane];
    float ss = v.x * v.x + v.y * v.y;
    #pragma unroll
    for (int off = 32; off; off >>= 1) ss += __shfl_xor(ss, off);
    float rn = rsqrtf(ss) * LOG2E_;        // exp2 domain
    __hip_bfloat162 o;
    o.x = __float2bfloat16(v.x * rn);
    o.y = __float2bfloat16(v.y * rn);
    ((__hip_bfloat162*)(Qn + (size_t)w * D_))[lane] = o;
}

// ---- kernel 3: main  sum_v exp2(q . k_v)  via bf16 MFMA ----
// Block 128q x 64v (4 waves); wave 64q x 32v (m=4, nn=2).
// LDS: row-major [64][256B] K tile, 16B-slot swizzle slot'=slot^(row&7),
// double-buffered (2x16KB). Staging COALESCED (source permuted within rows);
// ds_read_b128 conflict-free via the same XOR. Counted vmcnt(4) + raw
// s_barrier (never drain-0 in loop). exp2 deferred one tile via two acc
// banks so VALU overlaps the MFMA pipe within each wave.
__global__ __launch_bounds__(256, 2) void ce_main(
    const __hip_bfloat16* __restrict__ Qn,
    const __hip_bfloat16* __restrict__ Kn,
    float* __restrict__ Ssum)
{
    __shared__ char klds[32768];   // 2 x 16KB

    const int tid  = threadIdx.x;
    const int lane = tid & 63;
    const int wv   = tid >> 6;
    const int wr   = wv >> 1;      // q-half
    const int wc   = wv & 1;       // v col-half
    const int r0   = lane & 15;
    const int hi   = lane >> 4;
    const int r3   = r0 & 7;

    // XCD-aware remap: each XCD owns 2 whole splits (all 32 nb of each)
    const int fid  = blockIdx.y * 32 + blockIdx.x;
    const int xcd  = fid & 7;
    const int idx  = fid >> 3;
    const int split = xcd * 2 + (idx >> 5);
    const int nb    = idx & 31;

    // ---- Q fragments -> registers (loop-invariant) ----
    bf16x8 afr[4][4];
    {
        const char* qsrc = (const char*)Qn + (size_t)nb * 32768
                         + (wr * 64 + r0) * 256 + (hi << 4);
        #pragma unroll
        for (int m = 0; m < 4; ++m)
            #pragma unroll
            for (int kk = 0; kk < 4; ++kk)
                afr[m][kk] = *(const bf16x8*)(qsrc + m * 4096 + kk * 64);
    }

    // per-lane swizzled LDS read addresses (tile-invariant; static indexing)
    int raddr[2][4];
    #pragma unroll
    for (int nn = 0; nn < 2; ++nn)
        #pragma unroll
        for (int kk = 0; kk < 4; ++kk)
            raddr[nn][kk] = (wc * 32 + nn * 16 + r0) * 256
                          + (((kk * 4 + hi) ^ r3) << 4);

    // staging: thread covers bytes L = i*4096 + tid*16 (linear LDS dest);
    // source permuted within its 256B row: goff0 = row*256 + (slot^ (row&7))*16
    const int goff0 = ((tid >> 4) << 8) + (((tid & 15) ^ ((tid >> 4) & 7)) << 4);
    const char* kbase = (const char*)Kn + (size_t)split * 16384;  // +k*262144/tile

#define STAGE(k, CUR) do {                                                   \
        const char* s_ = kbase + (size_t)(k) * 262144 + goff0;               \
        char* d_ = klds + (CUR) + (tid << 4);                                \
        gload16(s_,          d_);                                            \
        gload16(s_ + 4096,   d_ + 4096);                                     \
        gload16(s_ + 8192,   d_ + 8192);                                     \
        gload16(s_ + 12288,  d_ + 12288);                                    \
    } while (0)

#define COMPUTE(CUR, ACC) do {                                               \
        bf16x8 b_[2][4];                                                     \
        _Pragma("unroll")                                                    \
        for (int nn = 0; nn < 2; ++nn)                                       \
            _Pragma("unroll")                                                \
            for (int kk = 0; kk < 4; ++kk)                                   \
                b_[nn][kk] = *(const bf16x8*)(klds + (CUR) + raddr[nn][kk]); \
        __builtin_amdgcn_s_setprio(1);                                       \
        _Pragma("unroll")                                                    \
        for (int m = 0; m < 4; ++m) {                                        \
            ACC[m][0] = __builtin_amdgcn_mfma_f32_16x16x32_bf16(afr[m][0], b_[0][0], fz, 0, 0, 0); \
            ACC[m][1] = __builtin_amdgcn_mfma_f32_16x16x32_bf16(afr[m][0], b_[1][0], fz, 0, 0, 0); \
        }                                                                    \
        _Pragma("unroll")                                                    \
        for (int kk = 1; kk < 4; ++kk)                                       \
            _Pragma("unroll")                                                \
            for (int m = 0; m < 4; ++m) {                                    \
                ACC[m][0] = __builtin_amdgcn_mfma_f32_16x16x32_bf16(afr[m][kk], b_[0][kk], ACC[m][0], 0, 0, 0); \
                ACC[m][1] = __builtin_amdgcn_mfma_f32_16x16x32_bf16(afr[m][kk], b_[1][kk], ACC[m][1], 0, 0, 0); \
            }                                                                \
        __builtin_amdgcn_s_setprio(0);                                       \
    } while (0)

#define EXP2S(ACC) do {                                                      \
        _Pragma("unroll")                                                    \
        for (int m = 0; m < 4; ++m)                                          \
            _Pragma("unroll")                                                \
            for (int q = 0; q < 4; ++q)                                      \
                psum[m][q] += exp2_fast(ACC[m][0][q]) + exp2_fast(ACC[m][1][q]); \
    } while (0)

#define WAITBAR(NSTR) do {                                                   \
        asm volatile("s_waitcnt vmcnt(" NSTR ")" ::: "memory");              \
        __builtin_amdgcn_s_barrier();                                        \
        __builtin_amdgcn_sched_barrier(0);                                   \
    } while (0)

    float psum[4][4];
    #pragma unroll
    for (int m = 0; m < 4; ++m)
        #pragma unroll
        for (int q = 0; q < 4; ++q) psum[m][q] = 0.f;

    const f32x4 fz = {0.f, 0.f, 0.f, 0.f};
    f32x4 accE[4][2], accO[4][2];
    #pragma unroll
    for (int m = 0; m < 4; ++m)
        #pragma unroll
        for (int nn = 0; nn < 2; ++nn)
            accO[m][nn] = (f32x4){-16384.f, -16384.f, -16384.f, -16384.f}; // exp2 -> 0

    // ---- prologue: stage tile 0, drain everything once ----
    STAGE(0, 0);
    asm volatile("s_waitcnt vmcnt(0)" ::: "memory");
    __builtin_amdgcn_s_barrier();
    __builtin_amdgcn_sched_barrier(0);

    #pragma unroll 1
    for (int j = 0; j < 96; j += 2) {
        // even tile j: read buf0, exp2 previous odd bank
        STAGE(j + 1, 16384);
        WAITBAR("4");                       // stage(j) complete everywhere
        COMPUTE(0, accE);
        EXP2S(accO);
        __builtin_amdgcn_s_barrier();       // buf0 reads done -> next STAGE may overwrite
        __builtin_amdgcn_sched_barrier(0);
        // odd tile j+1: read buf1
        STAGE(j + 2, 0);
        WAITBAR("4");                       // stage(j+1) complete everywhere
        COMPUTE(16384, accO);
        EXP2S(accE);
        __builtin_amdgcn_s_barrier();
        __builtin_amdgcn_sched_barrier(0);
    }
    // epilogue: tiles 96 (buf0) and 97 (buf1)
    STAGE(97, 16384);
    WAITBAR("4");                           // stage(96) done
    COMPUTE(0, accE);
    EXP2S(accO);
    WAITBAR("0");                           // stage(97) done everywhere
    COMPUTE(16384, accO);
    EXP2S(accE);
    EXP2S(accO);                            // tail: tile 97's bank

#undef STAGE
#undef COMPUTE
#undef EXP2S
#undef WAITBAR

    // reduce over 16 lanes (same q-rows, different v-cols), then atomics
    #pragma unroll
    for (int m = 0; m < 4; ++m) {
        #pragma unroll
        for (int q = 0; q < 4; ++q) {
            float v = psum[m][q];
            v += __shfl_xor(v, 1);
            v += __shfl_xor(v, 2);
            v += __shfl_xor(v, 4);
            v += __shfl_xor(v, 8);
            if (r0 == 0) {
                int row = nb * 128 + wr * 64 + m * 16 + hi * 4 + q;
                atomicAdd(&Ssum[row], v);
            }
        }
    }
}

// ---- kernel 4: per-row term = log(S - PADROWS) - true_logit ----
__global__ void term_kernel(const __hip_bfloat16* __restrict__ Qn,
                            const __hip_bfloat16* __restrict__ Kn,
                            const int* __restrict__ labels,
                            const float* __restrict__ Ssum,
                            float* __restrict__ T) {
    int w = (blockIdx.x * blockDim.x + threadIdx.x) >> 6;
    int lane = threadIdx.x & 63;
    if (w >= N_) return;
    int lab = labels[w];
    __hip_bfloat162 q2 = ((const __hip_bfloat162*)(Qn + (size_t)w * D_))[lane];
    __hip_bfloat162 k2 = ((const __hip_bfloat162*)(Kn + (size_t)lab * D_))[lane];
    float d = __bfloat162float(q2.x) * __bfloat162float(k2.x)
            + __bfloat162float(q2.y) * __bfloat162float(k2.y);
    #pragma unroll
    for (int off = 32; off; off >>= 1) d += __shfl_xor(d, off);
    if (lane == 0) T[w] = logf(Ssum[w] - PADROWS_) - d * LN2_;
}

// ---- kernel 5: mean over N ----
__global__ void reduce_kernel(const float* __restrict__ T, float* __restrict__ out) {
    __shared__ float sm[4];
    float s = 0.f;
    for (int i = threadIdx.x; i < N_; i += 256) s += T[i];
    #pragma unroll
    for (int off = 32; off; off >>= 1) s += __shfl_xor(s, off);
    if ((threadIdx.x & 63) == 0) sm[threadIdx.x >> 6] = s;
    __syncthreads();
    if (threadIdx.x == 0) out[0] = (sm[0] + sm[1] + sm[2] + sm[3]) * (1.0f / (float)N_);
}

extern "C" void kernel_launch(void* const* d_in, const int* in_sizes, int n_in,
                              void* d_out, int out_size, void* d_ws, size_t ws_size,
                              hipStream_t stream) {
    (void)in_sizes; (void)n_in; (void)out_size; (void)ws_size;
    const float* Q   = (const float*)d_in[0];
    const float* K   = (const float*)d_in[1];
    const int* loc   = (const int*)d_in[2];
    const int* labels= (const int*)d_in[3];
    float* out = (float*)d_out;

    char* ws = (char*)d_ws;
    __hip_bfloat16* Kn = (__hip_bfloat16*)ws;                       // VPAD_*128*2 = 25,690,112 B
    __hip_bfloat16* Qn = (__hip_bfloat16*)(ws + 25690112);          // N_*128*2   =  1,048,576 B
    float* Ssum        = (float*)(ws + 25690112 + 1048576);         // N_*4
    float* T           = Ssum + N_;                                  // N_*4

    knorm_kernel<<<VPAD_ / 4, 256, 0, stream>>>(K, Kn);
    qnorm_kernel<<<N_ / 4, 256, 0, stream>>>(Q, loc, Qn, Ssum);
    ce_main<<<dim3(32, NSPLIT_), 256, 0, stream>>>(Qn, Kn, Ssum);
    term_kernel<<<N_ / 4, 256, 0, stream>>>(Qn, Kn, labels, Ssum, T);
    reduce_kernel<<<1, 256, 0, stream>>>(T, out);
}